// Round 1
// baseline (226.564 us; speedup 1.0000x reference)
//
#include <hip/hip_runtime.h>
#include <hip/hip_bf16.h>

typedef unsigned int u32;
typedef unsigned short u16;
using f32x4 = __attribute__((ext_vector_type(4))) float;
using u32x4 = __attribute__((ext_vector_type(4))) u32;
using s16x8 = __attribute__((ext_vector_type(8))) short;

#define DEV static __device__ __forceinline__

DEV u32 pk2(float a, float b) {
  u16 lo = __builtin_bit_cast(u16, __float2bfloat16(a));
  u16 hi = __builtin_bit_cast(u16, __float2bfloat16(b));
  return (u32)lo | ((u32)hi << 16);
}

DEV f32x4 MFMA(u32x4 a, u32x4 b, f32x4 c) {
  return __builtin_amdgcn_mfma_f32_16x16x32_bf16(
      __builtin_bit_cast(s16x8, a), __builtin_bit_cast(s16x8, b), c, 0, 0, 0);
}

typedef const __attribute__((address_space(1))) u32 gu32;
typedef __attribute__((address_space(3))) u32 lu32;

DEV void load_lds16(const void* g, void* l) {
  __builtin_amdgcn_global_load_lds((gu32*)g, (lu32*)l, 16, 0, 0);
}

// ---------------- pre-kernel 1: per-expert alpha = mean(|W|) ----------------
__global__ void qalpha(const float* __restrict__ w1, const float* __restrict__ w2,
                       float* __restrict__ alphas) {
  int b = blockIdx.x;               // 0..7 -> w1 experts, 8..15 -> w2 experts
  const float* src = (b < 8 ? w1 : w2) + (size_t)(b & 7) * 32768;
  int tid = threadIdx.x;
  float s = 0.f;
  for (int i = tid; i < 32768; i += 256) s += fabsf(src[i]);
  #pragma unroll
  for (int off = 32; off >= 1; off >>= 1) s += __shfl_down(s, off, 64);
  __shared__ float ws4[4];
  if ((tid & 63) == 0) ws4[tid >> 6] = s;
  __syncthreads();
  if (tid == 0) alphas[b] = (ws4[0] + ws4[1] + ws4[2] + ws4[3]) * (1.f / 32768.f);
}

DEV u16 tq1(float v, float thr) {
  return (fabsf(v) > thr) ? (v > 0.f ? (u16)0x3F80 : (u16)0xBF80) : (u16)0;
}
DEV u32 tq2(float a, float b, float thr) {
  return (u32)tq1(a, thr) | ((u32)tq1(b, thr) << 16);
}

// ------------- pre-kernel 2: build pre-swizzled bf16 weight images -------------
// img1[e]: 256 rows (h) x 256B; byte = h*256 + ((2*d) ^ ((h&15)<<3))
// img2[e]: 128 rows (o) x 512B; byte = o*512 + ((2*k) ^ ((o&15)<<3))
// b2img  : 128 rows (o) x 64B;  byte = o*64  + ((2*k) ^ ((o&7)<<3)), k<8 = b2[k][o] else 0
__global__ void qimg(const float* __restrict__ w1, const float* __restrict__ w2,
                     const float* __restrict__ b2, const float* __restrict__ alphas,
                     char* __restrict__ img1, char* __restrict__ img2,
                     char* __restrict__ b2i) {
  int gid = blockIdx.x * 256 + threadIdx.x;
  if (gid < 65536) {
    int e = gid >> 13, rem = gid & 8191, h = rem >> 5, dg = rem & 31;
    float4 v = *(const float4*)(w1 + (size_t)e * 32768 + h * 128 + dg * 4);
    float thr = 0.5f * alphas[e];
    u32 lo = tq2(v.x, v.y, thr), hi = tq2(v.z, v.w, thr);
    char* dst = img1 + (size_t)e * 65536 + h * 256 + ((u32)(8 * dg) ^ ((u32)(h & 15) << 3));
    *(uint2*)dst = make_uint2(lo, hi);
  } else if (gid < 131072) {
    int idx = gid - 65536;
    int e = idx >> 13, rem = idx & 8191, o = rem >> 6, kg = rem & 63;
    float4 v = *(const float4*)(w2 + (size_t)e * 32768 + o * 256 + kg * 4);
    float thr = 0.5f * alphas[8 + e];
    u32 lo = tq2(v.x, v.y, thr), hi = tq2(v.z, v.w, thr);
    char* dst = img2 + (size_t)e * 65536 + o * 512 + ((u32)(8 * kg) ^ ((u32)(o & 15) << 3));
    *(uint2*)dst = make_uint2(lo, hi);
  } else if (gid < 132096) {
    int idx = gid - 131072;
    int o = idx >> 3, kg = idx & 7;
    float v[4];
    #pragma unroll
    for (int j = 0; j < 4; ++j) {
      int k = kg * 4 + j;
      v[j] = (k < 8) ? b2[k * 128 + o] : 0.f;
    }
    u32 lo = pk2(v[0], v[1]), hi = pk2(v[2], v[3]);
    char* dst = b2i + o * 64 + ((u32)(8 * kg) ^ ((u32)(o & 7) << 3));
    *(uint2*)dst = make_uint2(lo, hi);
  }
}

// ---------------- main fused kernel ----------------
#define SMEM_W1 0
#define SMEM_W2 65536
#define SMEM_B1 131072
#define SMEM_B2 139264
#define SMEM_G  147456
#define SMEM_BYTES 156672

__global__ __launch_bounds__(512, 2) void moe_main(
    const float* __restrict__ x, const float* __restrict__ b1,
    const float* __restrict__ wg, const float* __restrict__ bg,
    const char* __restrict__ img1, const char* __restrict__ img2,
    const char* __restrict__ b2i, float* __restrict__ out) {
  extern __shared__ char smem[];
  float* gbuf = (float*)(smem + SMEM_G);   // [256][9] f32 gate weights
  const int tid = threadIdx.x;
  const int w = tid >> 6, l = tid & 63, m = l & 15, g4 = l >> 4;
  const u32 swz = (u32)(m << 3);
  const int tok0 = blockIdx.x * 256;

  // ---- issue async staging: w1[0], w2[0], b1 (8KB), b2img (8KB)
  {
    const char* s1 = img1 + (size_t)(w * 8192);
    const char* s2 = img2 + (size_t)(w * 8192);
    #pragma unroll
    for (int i = 0; i < 8; ++i)
      load_lds16(s1 + i * 1024 + l * 16, smem + SMEM_W1 + w * 8192 + i * 1024);
    #pragma unroll
    for (int i = 0; i < 8; ++i)
      load_lds16(s2 + i * 1024 + l * 16, smem + SMEM_W2 + w * 8192 + i * 1024);
    if (w < 4) {
      #pragma unroll
      for (int i = 0; i < 2; ++i)
        load_lds16((const char*)b1 + (w * 2 + i) * 1024 + l * 16,
                   smem + SMEM_B1 + (w * 2 + i) * 1024);
    } else {
      #pragma unroll
      for (int i = 0; i < 2; ++i)
        load_lds16(b2i + ((w - 4) * 2 + i) * 1024 + l * 16,
                   smem + SMEM_B2 + ((w - 4) * 2 + i) * 1024);
    }
  }

  // ---- x fragments (B operand of GEMM1), kept in registers for whole kernel
  u32x4 xf[2][4];
  #pragma unroll
  for (int tt = 0; tt < 2; ++tt) {
    #pragma unroll
    for (int ks = 0; ks < 4; ++ks) {
      const float* xp = x + (size_t)(tok0 + w * 32 + tt * 16 + m) * 128 + ks * 32 + g4 * 4;
      float4 lo = *(const float4*)xp;
      float4 hi = *(const float4*)(xp + 16);
      xf[tt][ks][0] = pk2(lo.x, lo.y);
      xf[tt][ks][1] = pk2(lo.z, lo.w);
      xf[tt][ks][2] = pk2(hi.x, hi.y);
      xf[tt][ks][3] = pk2(hi.z, hi.w);
    }
  }

  // ---- gate phase 1: logits/T -> gbuf
  {
    int t = tid >> 1;
    int eb = (tid & 1) * 4;
    const float4* xr = (const float4*)(x + (size_t)(tok0 + t) * 128);
    const float4* wr = (const float4*)wg;
    float a0 = 0, a1 = 0, a2 = 0, a3 = 0;
    for (int i = 0; i < 32; ++i) {
      float4 xv = xr[i];
      float4 w0 = wr[(eb + 0) * 32 + i];
      float4 w1v = wr[(eb + 1) * 32 + i];
      float4 w2v = wr[(eb + 2) * 32 + i];
      float4 w3 = wr[(eb + 3) * 32 + i];
      a0 += xv.x * w0.x + xv.y * w0.y + xv.z * w0.z + xv.w * w0.w;
      a1 += xv.x * w1v.x + xv.y * w1v.y + xv.z * w1v.z + xv.w * w1v.w;
      a2 += xv.x * w2v.x + xv.y * w2v.y + xv.z * w2v.z + xv.w * w2v.w;
      a3 += xv.x * w3.x + xv.y * w3.y + xv.z * w3.z + xv.w * w3.w;
    }
    const float invT = 0.36787944117144233f;  // 1/e
    gbuf[t * 9 + eb + 0] = (a0 + bg[eb + 0]) * invT;
    gbuf[t * 9 + eb + 1] = (a1 + bg[eb + 1]) * invT;
    gbuf[t * 9 + eb + 2] = (a2 + bg[eb + 2]) * invT;
    gbuf[t * 9 + eb + 3] = (a3 + bg[eb + 3]) * invT;
  }
  __syncthreads();   // logits visible; all staging drained (vmcnt0 before barrier)

  // ---- gate phase 2: softmax + top-5 + renorm
  if (tid < 256) {
    float s[8];
    #pragma unroll
    for (int e = 0; e < 8; ++e) s[e] = gbuf[tid * 9 + e];
    float mx = s[0];
    #pragma unroll
    for (int e = 1; e < 8; ++e) mx = fmaxf(mx, s[e]);
    float p[8], den = 0.f;
    #pragma unroll
    for (int e = 0; e < 8; ++e) { p[e] = __expf(s[e] - mx); den += p[e]; }
    float inv = 1.f / den;
    #pragma unroll
    for (int e = 0; e < 8; ++e) p[e] *= inv;
    float gsel[8], wsum = 0.f;
    #pragma unroll
    for (int e = 0; e < 8; ++e) {
      int rank = 0;
      #pragma unroll
      for (int e2 = 0; e2 < 8; ++e2)
        rank += (p[e2] > p[e]) || (p[e2] == p[e] && e2 < e);
      gsel[e] = (rank < 5) ? p[e] : 0.f;
      wsum += gsel[e];
    }
    float r = 1.f / (wsum + 1e-8f);
    #pragma unroll
    for (int e = 0; e < 8; ++e) gbuf[tid * 9 + e] = gsel[e] * r;
  }
  __syncthreads();

  // ---- init acc2[o][t] = sum_e g[t][e]*b2[e][o] via one K=32 MFMA pass
  f32x4 acc2[8][2];
  {
    u32x4 gf[2];
    #pragma unroll
    for (int tt = 0; tt < 2; ++tt) {
      u32 p0 = 0, p1 = 0;
      if (g4 < 2) {
        const float* gr = gbuf + (w * 32 + tt * 16 + m) * 9 + g4 * 4;
        p0 = pk2(gr[0], gr[1]);
        p1 = pk2(gr[2], gr[3]);
      }
      gf[tt] = (u32x4){p0, p1, 0u, 0u};
    }
    const char* pb2 = smem + SMEM_B2 + m * 64;
    u32 swz7 = (u32)((m & 7) << 3);
    #pragma unroll
    for (int ot = 0; ot < 8; ++ot) {
      u32 olo = ((u32)(8 * g4)) ^ swz7;
      u32 ohi = ((u32)(32 + 8 * g4)) ^ swz7;
      uint2 lo = *(const uint2*)(pb2 + ot * 1024 + olo);
      uint2 hi = *(const uint2*)(pb2 + ot * 1024 + ohi);
      u32x4 af = (u32x4){lo.x, lo.y, hi.x, hi.y};
      #pragma unroll
      for (int tt = 0; tt < 2; ++tt)
        acc2[ot][tt] = MFMA(af, gf[tt], (f32x4){0.f, 0.f, 0.f, 0.f});
    }
  }

  // ---- expert loop
  const char* pw1 = smem + SMEM_W1 + m * 256;
  const char* pw2 = smem + SMEM_W2 + m * 512;
  #pragma unroll 1
  for (int e = 0; e < 8; ++e) {
    if (e > 0) {
      __syncthreads();  // everyone done reading previous expert's buffers
      const char* s1 = img1 + (size_t)e * 65536 + w * 8192;
      const char* s2 = img2 + (size_t)e * 65536 + w * 8192;
      #pragma unroll
      for (int i = 0; i < 8; ++i)
        load_lds16(s1 + i * 1024 + l * 16, smem + SMEM_W1 + w * 8192 + i * 1024);
      #pragma unroll
      for (int i = 0; i < 8; ++i)
        load_lds16(s2 + i * 1024 + l * 16, smem + SMEM_W2 + w * 8192 + i * 1024);
    }
    __syncthreads();   // staging arrived

    float gt[2];
    gt[0] = gbuf[(w * 32 + m) * 9 + e];
    gt[1] = gbuf[(w * 32 + 16 + m) * 9 + e];
    const float* b1e = (const float*)(smem + SMEM_B1) + e * 256 + g4 * 4;

    #pragma unroll
    for (int c = 0; c < 4; ++c) {
      f32x4 b1v[4];
      #pragma unroll
      for (int h = 0; h < 4; ++h)
        b1v[h] = *(const f32x4*)(b1e + c * 64 + h * 16);

      // GEMM1 chunk: D1[h][t], h in [64c, 64c+64)
      f32x4 a1[4][2];
      #pragma unroll
      for (int h = 0; h < 4; ++h)
        #pragma unroll
        for (int tt = 0; tt < 2; ++tt) a1[h][tt] = (f32x4){0.f, 0.f, 0.f, 0.f};

      #pragma unroll
      for (int ks = 0; ks < 4; ++ks) {
        u32x4 wf[4];
        u32 olo = ((u32)(ks * 64 + 8 * g4)) ^ swz;
        u32 ohi = ((u32)(ks * 64 + 32 + 8 * g4)) ^ swz;
        #pragma unroll
        for (int h = 0; h < 4; ++h) {
          const char* rb = pw1 + (c * 64 + h * 16) * 256;
          uint2 lo = *(const uint2*)(rb + olo);
          uint2 hi = *(const uint2*)(rb + ohi);
          wf[h] = (u32x4){lo.x, lo.y, hi.x, hi.y};
        }
        #pragma unroll
        for (int h = 0; h < 4; ++h)
          #pragma unroll
          for (int tt = 0; tt < 2; ++tt)
            a1[h][tt] = MFMA(wf[h], xf[tt][ks], a1[h][tt]);
      }

      // epilogue: relu(+b1), scale by gate, pack -> GEMM2 B-fragments (in-register)
      u32x4 hf[2][2];
      #pragma unroll
      for (int h = 0; h < 4; ++h) {
        #pragma unroll
        for (int tt = 0; tt < 2; ++tt) {
          f32x4 v = a1[h][tt];
          float gtv = gt[tt];
          float h0 = fmaxf(v.x + b1v[h].x, 0.f) * gtv;
          float h1 = fmaxf(v.y + b1v[h].y, 0.f) * gtv;
          float h2 = fmaxf(v.z + b1v[h].z, 0.f) * gtv;
          float h3 = fmaxf(v.w + b1v[h].w, 0.f) * gtv;
          hf[h >> 1][tt][(h & 1) * 2 + 0] = pk2(h0, h1);
          hf[h >> 1][tt][(h & 1) * 2 + 1] = pk2(h2, h3);
        }
      }

      // GEMM2 partial: acc2[o][t] += w2q[o][k] * hid'[k][t], k in [64c, 64c+64)
      #pragma unroll
      for (int k2 = 0; k2 < 2; ++k2) {
        u32 olo = ((u32)(c * 128 + k2 * 64 + 8 * g4)) ^ swz;
        u32 ohi = ((u32)(c * 128 + k2 * 64 + 32 + 8 * g4)) ^ swz;
        #pragma unroll
        for (int ot = 0; ot < 8; ++ot) {
          const char* rb = pw2 + ot * 16 * 512;
          uint2 lo = *(const uint2*)(rb + olo);
          uint2 hi = *(const uint2*)(rb + ohi);
          u32x4 af = (u32x4){lo.x, lo.y, hi.x, hi.y};
          #pragma unroll
          for (int tt = 0; tt < 2; ++tt)
            acc2[ot][tt] = MFMA(af, hf[k2][tt], acc2[ot][tt]);
        }
      }
    }
  }

  // ---- store D2[o][t] -> out[t][o]
  #pragma unroll
  for (int ot = 0; ot < 8; ++ot) {
    #pragma unroll
    for (int tt = 0; tt < 2; ++tt) {
      float* op = out + (size_t)(tok0 + w * 32 + tt * 16 + m) * 128 + ot * 16 + g4 * 4;
      *(f32x4*)op = acc2[ot][tt];
    }
  }
}

extern "C" void kernel_launch(void* const* d_in, const int* in_sizes, int n_in,
                              void* d_out, int out_size, void* d_ws, size_t ws_size,
                              hipStream_t stream) {
  const float* x  = (const float*)d_in[0];
  const float* w1 = (const float*)d_in[1];
  const float* b1 = (const float*)d_in[2];
  const float* w2 = (const float*)d_in[3];
  const float* b2 = (const float*)d_in[4];
  const float* wg = (const float*)d_in[5];
  const float* bg = (const float*)d_in[6];
  float* out = (float*)d_out;

  if (ws_size < 1056832) return;  // need ~1.03 MB scratch for weight images
  char* ws = (char*)d_ws;
  char* img1 = ws;                       // 8 * 64KB
  char* img2 = ws + 524288;              // 8 * 64KB
  char* b2i  = ws + 1048576;             // 8KB
  float* alphas = (float*)(ws + 1056768);

  int ntok = in_sizes[0] / 128;
  int nblk = ntok / 256;

  qalpha<<<16, 256, 0, stream>>>(w1, w2, alphas);
  qimg<<<516, 256, 0, stream>>>(w1, w2, b2, alphas, img1, img2, b2i);

  hipFuncSetAttribute(reinterpret_cast<const void*>(moe_main),
                      hipFuncAttributeMaxDynamicSharedMemorySize, SMEM_BYTES);
  moe_main<<<nblk, 512, SMEM_BYTES, stream>>>(x, b1, wg, bg, img1, img2, b2i, out);
}

// Round 2
// 188.740 us; speedup vs baseline: 1.2004x; 1.2004x over previous
//
#include <hip/hip_runtime.h>
#include <hip/hip_bf16.h>

typedef unsigned int u32;
typedef unsigned short u16;
using f32x4  = __attribute__((ext_vector_type(4))) float;
using f32x16 = __attribute__((ext_vector_type(16))) float;
using u32x4  = __attribute__((ext_vector_type(4))) u32;
using s16x8  = __attribute__((ext_vector_type(8))) short;

#define DEV static __device__ __forceinline__

DEV u32 pk2(float a, float b) {
  u16 lo = __builtin_bit_cast(u16, __float2bfloat16(a));
  u16 hi = __builtin_bit_cast(u16, __float2bfloat16(b));
  return (u32)lo | ((u32)hi << 16);
}

DEV f32x16 MFMA32(u32x4 a, u32x4 b, f32x16 c) {
  return __builtin_amdgcn_mfma_f32_32x32x16_bf16(
      __builtin_bit_cast(s16x8, a), __builtin_bit_cast(s16x8, b), c, 0, 0, 0);
}

// swaps upper 32 lanes of a with lower 32 lanes of b:
// a' = {a.lo | b.lo}, b' = {a.hi | b.hi}
DEV void pl32swap(u32& a, u32& b) {
  asm volatile("v_permlane32_swap_b32 %0, %1" : "+v"(a), "+v"(b));
}

typedef const __attribute__((address_space(1))) u32 gu32;
typedef __attribute__((address_space(3))) u32 lu32;

DEV void load_lds16(const void* g, void* l) {
  __builtin_amdgcn_global_load_lds((gu32*)g, (lu32*)l, 16, 0, 0);
}

// ---------------- pre-kernel 1: per-expert alpha = mean(|W|) ----------------
__global__ void qalpha(const float* __restrict__ w1, const float* __restrict__ w2,
                       float* __restrict__ alphas) {
  int b = blockIdx.x;  // 0..7 -> w1 experts, 8..15 -> w2 experts
  const float* src = (b < 8 ? w1 : w2) + (size_t)(b & 7) * 32768;
  int tid = threadIdx.x;
  float s = 0.f;
  for (int i = tid; i < 32768; i += 256) s += fabsf(src[i]);
  #pragma unroll
  for (int off = 32; off >= 1; off >>= 1) s += __shfl_down(s, off, 64);
  __shared__ float ws4[4];
  if ((tid & 63) == 0) ws4[tid >> 6] = s;
  __syncthreads();
  if (tid == 0) alphas[b] = (ws4[0] + ws4[1] + ws4[2] + ws4[3]) * (1.f / 32768.f);
}

DEV u16 tq1(float v, float thr) {
  return (fabsf(v) > thr) ? (v > 0.f ? (u16)0x3F80 : (u16)0xBF80) : (u16)0;
}
DEV u32 tq2(float a, float b, float thr) {
  return (u32)tq1(a, thr) | ((u32)tq1(b, thr) << 16);
}

// ------------- pre-kernel 2: build pre-swizzled bf16 weight images -------------
// img1: [e][ht(8)][row(32)][256B]; 16B slot s(=ks*2+hi) at byte s*16 ^ ((row&15)<<4)
// img2: [e][c(8)][og(32)][256B];  slot s = (o&3)*4 + kslot, byte s*16 ^ ((og&7)<<4)
__global__ void qimg(const float* __restrict__ w1, const float* __restrict__ w2,
                     const float* __restrict__ alphas,
                     char* __restrict__ img1, char* __restrict__ img2) {
  int gid = blockIdx.x * 256 + threadIdx.x;
  if (gid < 32768) {
    // img1: one 16B slot = 8 consecutive k of one h row
    int e = gid >> 12, rem = gid & 4095;
    int h = rem >> 4, slot = rem & 15;
    int k0 = (slot >> 1) * 16 + (slot & 1) * 8;
    const float* src = w1 + (size_t)e * 32768 + h * 128 + k0;
    float thr = 0.5f * alphas[e];
    float4 v0 = *(const float4*)src;
    float4 v1 = *(const float4*)(src + 4);
    u32 q0 = tq2(v0.x, v0.y, thr), q1 = tq2(v0.z, v0.w, thr);
    u32 q2 = tq2(v1.x, v1.y, thr), q3 = tq2(v1.z, v1.w, thr);
    int ht = h >> 5, row = h & 31;
    char* dst = img1 + ((size_t)e << 16) + ht * 8192 + row * 256 +
                (((u32)slot * 16) ^ ((u32)(row & 15) << 4));
    *(uint4*)dst = make_uint4(q0, q1, q2, q3);
  } else if (gid < 65536) {
    // img2: one 16B slot = 8 consecutive k of one o row within chunk c
    int id = gid - 32768;
    int e = id >> 12, rem = id & 4095;
    int c = rem >> 9, o = (rem >> 2) & 127, kslot = rem & 3;
    int k0 = c * 32 + (kslot >> 1) * 16 + (kslot & 1) * 8;
    const float* src = w2 + (size_t)e * 32768 + o * 256 + k0;
    float thr = 0.5f * alphas[8 + e];
    float4 v0 = *(const float4*)src;
    float4 v1 = *(const float4*)(src + 4);
    u32 q0 = tq2(v0.x, v0.y, thr), q1 = tq2(v0.z, v0.w, thr);
    u32 q2 = tq2(v1.x, v1.y, thr), q3 = tq2(v1.z, v1.w, thr);
    int og = o >> 2, slot = (o & 3) * 4 + kslot;
    char* dst = img2 + ((size_t)e << 16) + c * 8192 + og * 256 +
                (((u32)slot * 16) ^ ((u32)(og & 7) << 4));
    *(uint4*)dst = make_uint4(q0, q1, q2, q3);
  }
}

// ---------------- main fused kernel ----------------
// LDS: [0,16K) dbuf0 (w1 8K | w2 8K), [16K,32K) dbuf1, [32K,40K) b1 f32,
//      [40K,44K) b2 f32, [44K..) gate buf [256][12 f32]
#define LDS_B1 32768
#define LDS_B2 40960
#define LDS_G  45056
#define SMEM_BYTES 57344

__global__ __launch_bounds__(256, 2) void moe_main(
    const float* __restrict__ x, const float* __restrict__ b1g,
    const float* __restrict__ b2g, const float* __restrict__ wg,
    const float* __restrict__ bg, const char* __restrict__ img1,
    const char* __restrict__ img2, float* __restrict__ out) {
  extern __shared__ char smem[];
  const int tid = threadIdx.x;
  const int w = tid >> 6, l = tid & 63;
  const int col = l & 31, hi = l >> 5;
  const int tokw = blockIdx.x * 256 + w * 64;  // wave's token base

  // ---- issue async staging: chunk 0 (e=0,ht=0 w1 + e=0,c=0 w2), b1, b2
  {
    const char* s1 = img1 + w * 2048 + l * 16;
    const char* s2 = img2 + w * 2048 + l * 16;
    load_lds16(s1,        smem + w * 2048);
    load_lds16(s1 + 1024, smem + w * 2048 + 1024);
    load_lds16(s2,        smem + 8192 + w * 2048);
    load_lds16(s2 + 1024, smem + 8192 + w * 2048 + 1024);
    load_lds16((const char*)b1g + w * 2048 + l * 16, smem + LDS_B1 + w * 2048);
    load_lds16((const char*)b1g + w * 2048 + 1024 + l * 16,
               smem + LDS_B1 + w * 2048 + 1024);
    load_lds16((const char*)b2g + w * 1024 + l * 16, smem + LDS_B2 + w * 1024);
  }

  // ---- xf: x fragments (B operand of GEMM1), bf16, kept in regs all kernel
  u32x4 xf[2][8];
  #pragma unroll
  for (int tt = 0; tt < 2; ++tt) {
    #pragma unroll
    for (int ks = 0; ks < 8; ++ks) {
      const float* xp = x + (size_t)(tokw + tt * 32 + col) * 128 + ks * 16 + hi * 8;
      float4 v0 = *(const float4*)xp;
      float4 v1 = *(const float4*)(xp + 4);
      xf[tt][ks] = (u32x4){pk2(v0.x, v0.y), pk2(v0.z, v0.w),
                           pk2(v1.x, v1.y), pk2(v1.z, v1.w)};
    }
  }

  // ---- gate: exact f32 logits -> softmax/T -> top-5 -> renorm -> gbuf
  {
    int t = blockIdx.x * 256 + tid;
    const float4* xr = (const float4*)(x + (size_t)t * 128);
    const float4* wr = (const float4*)wg;
    float lg[8];
    #pragma unroll
    for (int e = 0; e < 8; ++e) lg[e] = bg[e];
    for (int i = 0; i < 32; ++i) {
      float4 xv = xr[i];
      #pragma unroll
      for (int e = 0; e < 8; ++e) {
        float4 wv = wr[e * 32 + i];
        lg[e] += xv.x * wv.x + xv.y * wv.y + xv.z * wv.z + xv.w * wv.w;
      }
    }
    const float invT = 0.36787944117144233f;  // 1/e
    #pragma unroll
    for (int e = 0; e < 8; ++e) lg[e] *= invT;
    float mx = lg[0];
    #pragma unroll
    for (int e = 1; e < 8; ++e) mx = fmaxf(mx, lg[e]);
    float p[8], den = 0.f;
    #pragma unroll
    for (int e = 0; e < 8; ++e) { p[e] = __expf(lg[e] - mx); den += p[e]; }
    float inv = 1.f / den;
    #pragma unroll
    for (int e = 0; e < 8; ++e) p[e] *= inv;
    float gsel[8], wsum = 0.f;
    #pragma unroll
    for (int e = 0; e < 8; ++e) {
      int rank = 0;
      #pragma unroll
      for (int e2 = 0; e2 < 8; ++e2)
        rank += (p[e2] > p[e]) || (p[e2] == p[e] && e2 < e);
      gsel[e] = (rank < 5) ? p[e] : 0.f;
      wsum += gsel[e];
    }
    float r = 1.f / (wsum + 1e-8f);
    float* gr = (float*)(smem + LDS_G) + tid * 12;
    *(f32x4*)gr       = (f32x4){gsel[0] * r, gsel[1] * r, gsel[2] * r, gsel[3] * r};
    *(f32x4*)(gr + 4) = (f32x4){gsel[4] * r, gsel[5] * r, gsel[6] * r, gsel[7] * r};
  }
  __syncthreads();  // gbuf visible; all staging drained

  // ---- init acc2[ot][tt] = sum_e g[t][e]*b2[e][o] via one K=16 MFMA pass
  f32x16 acc2[4][2];
  {
    u32x4 gf[2];
    #pragma unroll
    for (int tt = 0; tt < 2; ++tt) {
      u32x4 v = (u32x4){0u, 0u, 0u, 0u};
      if (hi == 0) {
        const float* gr = (const float*)(smem + LDS_G) + (w * 64 + tt * 32 + col) * 12;
        f32x4 g0 = *(const f32x4*)gr;
        f32x4 g1 = *(const f32x4*)(gr + 4);
        v = (u32x4){pk2(g0.x, g0.y), pk2(g0.z, g0.w), pk2(g1.x, g1.y), pk2(g1.z, g1.w)};
      }
      gf[tt] = v;
    }
    const float* b2r = (const float*)(smem + LDS_B2);
    #pragma unroll
    for (int ot = 0; ot < 4; ++ot) {
      u32x4 af = (u32x4){0u, 0u, 0u, 0u};
      if (hi == 0) {
        int o = ot * 32 + col;
        af = (u32x4){pk2(b2r[0 * 128 + o], b2r[1 * 128 + o]),
                     pk2(b2r[2 * 128 + o], b2r[3 * 128 + o]),
                     pk2(b2r[4 * 128 + o], b2r[5 * 128 + o]),
                     pk2(b2r[6 * 128 + o], b2r[7 * 128 + o])};
      }
      f32x16 z{};
      #pragma unroll
      for (int tt = 0; tt < 2; ++tt) acc2[ot][tt] = MFMA32(af, gf[tt], z);
    }
  }

  // ---- chunk loop: 64 chunks = 8 experts x 8 h-tiles of 32
  const u32 rb1 = (u32)(col * 256);
  int cur = 0;
  for (int n = 0; n < 64; ++n) {
    const int e = n >> 3, ht = n & 7;
    if (n + 1 < 64) {  // issue next chunk into other buffer (overlaps compute)
      const int n1 = n + 1, e1 = n1 >> 3, ht1 = n1 & 7;
      const char* s1 = img1 + ((size_t)e1 << 16) + ht1 * 8192 + w * 2048 + l * 16;
      const char* s2 = img2 + ((size_t)e1 << 16) + ht1 * 8192 + w * 2048 + l * 16;
      char* d1 = smem + (cur ^ 1) * 16384 + w * 2048;
      char* d2 = smem + (cur ^ 1) * 16384 + 8192 + w * 2048;
      load_lds16(s1,        d1);
      load_lds16(s1 + 1024, d1 + 1024);
      load_lds16(s2,        d2);
      load_lds16(s2 + 1024, d2 + 1024);
    }

    // --- GEMM1: D1[32h x 64t] for h in [32*ht, 32*ht+32)
    const char* w1c = smem + cur * 16384;
    f32x16 a1_0{}, a1_1{};
    #pragma unroll
    for (int ks = 0; ks < 8; ++ks) {
      u32 off = rb1 + (((u32)(ks * 2 + hi) * 16) ^ ((u32)(l & 15) << 4));
      u32x4 frag = *(const u32x4*)(w1c + off);
      a1_0 = MFMA32(frag, xf[0][ks], a1_0);
      a1_1 = MFMA32(frag, xf[1][ks], a1_1);
    }

    // --- epilogue: +b1, relu, *gate, pack bf16, permlane -> GEMM2 B-frags
    u32x4 hf[2][2];
    const float* b1b = (const float*)(smem + LDS_B1) + e * 256 + ht * 32 + hi * 4;
    #pragma unroll
    for (int tt = 0; tt < 2; ++tt) {
      const f32x16& a1 = tt ? a1_1 : a1_0;
      float g = ((const float*)(smem + LDS_G))[(w * 64 + tt * 32 + col) * 12 + e];
      u32 u[8];
      #pragma unroll
      for (int rg = 0; rg < 4; ++rg) {
        f32x4 bb = *(const f32x4*)(b1b + rg * 8);
        float h0 = fmaxf(a1[rg * 4 + 0] + bb.x, 0.f) * g;
        float h1 = fmaxf(a1[rg * 4 + 1] + bb.y, 0.f) * g;
        float h2 = fmaxf(a1[rg * 4 + 2] + bb.z, 0.f) * g;
        float h3 = fmaxf(a1[rg * 4 + 3] + bb.w, 0.f) * g;
        u[rg * 2 + 0] = pk2(h0, h1);
        u[rg * 2 + 1] = pk2(h2, h3);
      }
      // rows held: u0={r01|r45} u1={r23|r67} u2={r89|r12,13} u3={r10,11|r14,15} (+16 for u4..7)
      pl32swap(u[0], u[2]);  // -> w0={r01|r89},   w2={r45|r12,13}
      pl32swap(u[1], u[3]);  // -> w1={r23|r10,11} w3={r67|r14,15}
      pl32swap(u[4], u[6]);
      pl32swap(u[5], u[7]);
      hf[0][tt] = (u32x4){u[0], u[1], u[2], u[3]};
      hf[1][tt] = (u32x4){u[4], u[5], u[6], u[7]};
    }

    // --- GEMM2: acc2[o][t] += w2q[o][k-slice] * hid[k-slice][t]
    const char* w2c = smem + cur * 16384 + 8192;
    #pragma unroll
    for (int ks2 = 0; ks2 < 2; ++ks2) {
      #pragma unroll
      for (int ot = 0; ot < 4; ++ot) {
        u32 og = (u32)(ot * 8 + (col >> 2));
        u32 slot = (u32)((col & 3) * 4 + ks2 * 2 + hi);
        u32 off = og * 256 + ((slot * 16) ^ ((og & 7) << 4));
        u32x4 af = *(const u32x4*)(w2c + off);
        acc2[ot][0] = MFMA32(af, hf[ks2][0], acc2[ot][0]);
        acc2[ot][1] = MFMA32(af, hf[ks2][1], acc2[ot][1]);
      }
    }
    __syncthreads();  // next chunk landed (vmcnt drain) + all done reading cur
    cur ^= 1;
  }

  // ---- store D2[o][t] -> out[t][o]
  #pragma unroll
  for (int ot = 0; ot < 4; ++ot) {
    #pragma unroll
    for (int tt = 0; tt < 2; ++tt) {
      const f32x16& a = acc2[ot][tt];
      float* op = out + (size_t)(tokw + tt * 32 + col) * 128 + ot * 32 + hi * 4;
      #pragma unroll
      for (int rg = 0; rg < 4; ++rg)
        *(f32x4*)(op + rg * 8) =
            (f32x4){a[rg * 4 + 0], a[rg * 4 + 1], a[rg * 4 + 2], a[rg * 4 + 3]};
    }
  }
}

extern "C" void kernel_launch(void* const* d_in, const int* in_sizes, int n_in,
                              void* d_out, int out_size, void* d_ws, size_t ws_size,
                              hipStream_t stream) {
  const float* x  = (const float*)d_in[0];
  const float* w1 = (const float*)d_in[1];
  const float* b1 = (const float*)d_in[2];
  const float* w2 = (const float*)d_in[3];
  const float* b2 = (const float*)d_in[4];
  const float* wg = (const float*)d_in[5];
  const float* bg = (const float*)d_in[6];
  float* out = (float*)d_out;

  if (ws_size < 1048640) return;
  char* ws = (char*)d_ws;
  char* img1 = ws;                        // 8 * 64KB
  char* img2 = ws + 524288;               // 8 * 64KB
  float* alphas = (float*)(ws + 1048576); // 16 f32

  int ntok = in_sizes[0] / 128;
  int nblk = ntok / 256;

  qalpha<<<16, 256, 0, stream>>>(w1, w2, alphas);
  qimg<<<256, 256, 0, stream>>>(w1, w2, alphas, img1, img2);

  hipFuncSetAttribute(reinterpret_cast<const void*>(moe_main),
                      hipFuncAttributeMaxDynamicSharedMemorySize, SMEM_BYTES);
  moe_main<<<nblk, 256, SMEM_BYTES, stream>>>(x, b1, b2, wg, bg, img1, img2, out);
}

// Round 3
// 187.217 us; speedup vs baseline: 1.2102x; 1.0081x over previous
//
#include <hip/hip_runtime.h>
#include <hip/hip_bf16.h>

typedef unsigned int u32;
typedef unsigned short u16;
using f32x4  = __attribute__((ext_vector_type(4))) float;
using f32x16 = __attribute__((ext_vector_type(16))) float;
using u32x4  = __attribute__((ext_vector_type(4))) u32;
using s16x8  = __attribute__((ext_vector_type(8))) short;

#define DEV static __device__ __forceinline__

DEV u32 pk2(float a, float b) {
  u16 lo = __builtin_bit_cast(u16, __float2bfloat16(a));
  u16 hi = __builtin_bit_cast(u16, __float2bfloat16(b));
  return (u32)lo | ((u32)hi << 16);
}

DEV f32x16 MFMA32(u32x4 a, u32x4 b, f32x16 c) {
  return __builtin_amdgcn_mfma_f32_32x32x16_bf16(
      __builtin_bit_cast(s16x8, a), __builtin_bit_cast(s16x8, b), c, 0, 0, 0);
}

// swaps upper 32 lanes of a with lower 32 lanes of b
DEV void pl32swap(u32& a, u32& b) {
  asm volatile("v_permlane32_swap_b32 %0, %1" : "+v"(a), "+v"(b));
}

typedef const __attribute__((address_space(1))) u32 gu32;
typedef __attribute__((address_space(3))) u32 lu32;

DEV void load_lds16(const void* g, void* l) {
  __builtin_amdgcn_global_load_lds((gu32*)g, (lu32*)l, 16, 0, 0);
}

// ---------------- pre-kernel 1: per-expert alpha = mean(|W|) ----------------
__global__ void qalpha(const float* __restrict__ w1, const float* __restrict__ w2,
                       float* __restrict__ alphas) {
  int b = blockIdx.x;  // 0..7 -> w1 experts, 8..15 -> w2 experts
  const float* src = (b < 8 ? w1 : w2) + (size_t)(b & 7) * 32768;
  int tid = threadIdx.x;
  float s = 0.f;
  for (int i = tid; i < 32768; i += 256) s += fabsf(src[i]);
  #pragma unroll
  for (int off = 32; off >= 1; off >>= 1) s += __shfl_down(s, off, 64);
  __shared__ float ws4[4];
  if ((tid & 63) == 0) ws4[tid >> 6] = s;
  __syncthreads();
  if (tid == 0) alphas[b] = (ws4[0] + ws4[1] + ws4[2] + ws4[3]) * (1.f / 32768.f);
}

DEV u16 tq1(float v, float thr) {
  return (fabsf(v) > thr) ? (v > 0.f ? (u16)0x3F80 : (u16)0xBF80) : (u16)0;
}
DEV u32 tq2(float a, float b, float thr) {
  return (u32)tq1(a, thr) | ((u32)tq1(b, thr) << 16);
}

// ------------- pre-kernel 2: build pre-swizzled bf16 weight images -------------
// img1: [e][ht(8)][row(32)][256B]; 16B slot s(=ks*2+hi) at byte s*16 ^ ((row&15)<<4)
// img2: [e][c(8)][og(32)][256B];  slot s = (o&3)*4 + kslot, byte s*16 ^ ((og&7)<<4)
__global__ void qimg(const float* __restrict__ w1, const float* __restrict__ w2,
                     const float* __restrict__ alphas,
                     char* __restrict__ img1, char* __restrict__ img2) {
  int gid = blockIdx.x * 256 + threadIdx.x;
  if (gid < 32768) {
    int e = gid >> 12, rem = gid & 4095;
    int h = rem >> 4, slot = rem & 15;
    int k0 = (slot >> 1) * 16 + (slot & 1) * 8;
    const float* src = w1 + (size_t)e * 32768 + h * 128 + k0;
    float thr = 0.5f * alphas[e];
    float4 v0 = *(const float4*)src;
    float4 v1 = *(const float4*)(src + 4);
    u32 q0 = tq2(v0.x, v0.y, thr), q1 = tq2(v0.z, v0.w, thr);
    u32 q2 = tq2(v1.x, v1.y, thr), q3 = tq2(v1.z, v1.w, thr);
    int ht = h >> 5, row = h & 31;
    char* dst = img1 + ((size_t)e << 16) + ht * 8192 + row * 256 +
                (((u32)slot * 16) ^ ((u32)(row & 15) << 4));
    *(uint4*)dst = make_uint4(q0, q1, q2, q3);
  } else if (gid < 65536) {
    int id = gid - 32768;
    int e = id >> 12, rem = id & 4095;
    int c = rem >> 9, o = (rem >> 2) & 127, kslot = rem & 3;
    int k0 = c * 32 + (kslot >> 1) * 16 + (kslot & 1) * 8;
    const float* src = w2 + (size_t)e * 32768 + o * 256 + k0;
    float thr = 0.5f * alphas[8 + e];
    float4 v0 = *(const float4*)src;
    float4 v1 = *(const float4*)(src + 4);
    u32 q0 = tq2(v0.x, v0.y, thr), q1 = tq2(v0.z, v0.w, thr);
    u32 q2 = tq2(v1.x, v1.y, thr), q3 = tq2(v1.z, v1.w, thr);
    int og = o >> 2, slot = (o & 3) * 4 + kslot;
    char* dst = img2 + ((size_t)e << 16) + c * 8192 + og * 256 +
                (((u32)slot * 16) ^ ((u32)(og & 7) << 4));
    *(uint4*)dst = make_uint4(q0, q1, q2, q3);
  }
}

// ---------------- main fused kernel ----------------
// LDS: ring[3] x 16K (w1 8K | w2 8K), B1 8K f32, B2 4K f32, G 8K f32 [8][256]
#define LDS_B1 49152
#define LDS_B2 57344
#define LDS_G  61440
#define SMEM_BYTES 69632

__global__ __launch_bounds__(256, 2) void moe_main(
    const float* __restrict__ x, const float* __restrict__ b1g,
    const float* __restrict__ b2g, const float* __restrict__ wg,
    const float* __restrict__ bg, const char* __restrict__ img1,
    const char* __restrict__ img2, float* __restrict__ out) {
  extern __shared__ char smem[];
  const int tid = threadIdx.x;
  const int w = tid >> 6, l = tid & 63;
  const int col = l & 31, hi = l >> 5;
  const int tokw = blockIdx.x * 256 + w * 64;  // wave's token base

  // ---- prologue staging: chunk0 -> ring0, chunk1 -> ring1, b1, b2
  {
    const char* s1 = img1 + w * 2048 + l * 16;
    const char* s2 = img2 + w * 2048 + l * 16;
    load_lds16(s1,        smem + w * 2048);
    load_lds16(s1 + 1024, smem + w * 2048 + 1024);
    load_lds16(s2,        smem + 8192 + w * 2048);
    load_lds16(s2 + 1024, smem + 8192 + w * 2048 + 1024);
    load_lds16(s1 + 8192,        smem + 16384 + w * 2048);
    load_lds16(s1 + 8192 + 1024, smem + 16384 + w * 2048 + 1024);
    load_lds16(s2 + 8192,        smem + 16384 + 8192 + w * 2048);
    load_lds16(s2 + 8192 + 1024, smem + 16384 + 8192 + w * 2048 + 1024);
    load_lds16((const char*)b1g + w * 2048 + l * 16, smem + LDS_B1 + w * 2048);
    load_lds16((const char*)b1g + w * 2048 + 1024 + l * 16,
               smem + LDS_B1 + w * 2048 + 1024);
    load_lds16((const char*)b2g + w * 1024 + l * 16, smem + LDS_B2 + w * 1024);
  }

  // ---- xf: x fragments (B operand of GEMM1), bf16, kept in regs all kernel
  u32x4 xf[2][8];
  #pragma unroll
  for (int tt = 0; tt < 2; ++tt) {
    #pragma unroll
    for (int ks = 0; ks < 8; ++ks) {
      const float* xp = x + (size_t)(tokw + tt * 32 + col) * 128 + ks * 16 + hi * 8;
      float4 v0 = *(const float4*)xp;
      float4 v1 = *(const float4*)(xp + 4);
      xf[tt][ks] = (u32x4){pk2(v0.x, v0.y), pk2(v0.z, v0.w),
                           pk2(v1.x, v1.y), pk2(v1.z, v1.w)};
    }
  }

  // ---- gate: exact f32 logits -> softmax/T -> top-5 -> renorm -> gT[8][256]
  {
    int t = blockIdx.x * 256 + tid;
    const float4* xr = (const float4*)(x + (size_t)t * 128);
    const float4* wr = (const float4*)wg;
    float lg[8];
    #pragma unroll
    for (int e = 0; e < 8; ++e) lg[e] = bg[e];
    for (int i = 0; i < 32; ++i) {
      float4 xv = xr[i];
      #pragma unroll
      for (int e = 0; e < 8; ++e) {
        float4 wv = wr[e * 32 + i];
        lg[e] += xv.x * wv.x + xv.y * wv.y + xv.z * wv.z + xv.w * wv.w;
      }
    }
    const float invT = 0.36787944117144233f;  // 1/e
    #pragma unroll
    for (int e = 0; e < 8; ++e) lg[e] *= invT;
    float mx = lg[0];
    #pragma unroll
    for (int e = 1; e < 8; ++e) mx = fmaxf(mx, lg[e]);
    float p[8], den = 0.f;
    #pragma unroll
    for (int e = 0; e < 8; ++e) { p[e] = __expf(lg[e] - mx); den += p[e]; }
    float inv = 1.f / den;
    #pragma unroll
    for (int e = 0; e < 8; ++e) p[e] *= inv;
    float gsel[8], wsum = 0.f;
    #pragma unroll
    for (int e = 0; e < 8; ++e) {
      int rank = 0;
      #pragma unroll
      for (int e2 = 0; e2 < 8; ++e2)
        rank += (p[e2] > p[e]) || (p[e2] == p[e] && e2 < e);
      gsel[e] = (rank < 5) ? p[e] : 0.f;
      wsum += gsel[e];
    }
    float r = 1.f / (wsum + 1e-8f);
    float* gT = (float*)(smem + LDS_G);
    #pragma unroll
    for (int e = 0; e < 8; ++e) gT[e * 256 + tid] = gsel[e] * r;
  }
  __syncthreads();  // gate visible; prologue staging drained (vmcnt 0)

  // ---- init acc2[ot][tt] = sum_e g[t][e]*b2[e][o] via one K=16 MFMA pass
  f32x16 acc2[4][2];
  {
    const float* gT = (const float*)(smem + LDS_G);
    u32x4 gf[2];
    #pragma unroll
    for (int tt = 0; tt < 2; ++tt) {
      u32x4 v = (u32x4){0u, 0u, 0u, 0u};
      if (hi == 0) {
        int t = w * 64 + tt * 32 + col;
        v = (u32x4){pk2(gT[0 * 256 + t], gT[1 * 256 + t]),
                    pk2(gT[2 * 256 + t], gT[3 * 256 + t]),
                    pk2(gT[4 * 256 + t], gT[5 * 256 + t]),
                    pk2(gT[6 * 256 + t], gT[7 * 256 + t])};
      }
      gf[tt] = v;
    }
    const float* b2r = (const float*)(smem + LDS_B2);
    #pragma unroll
    for (int ot = 0; ot < 4; ++ot) {
      u32x4 af = (u32x4){0u, 0u, 0u, 0u};
      if (hi == 0) {
        int o = ot * 32 + col;
        af = (u32x4){pk2(b2r[0 * 128 + o], b2r[1 * 128 + o]),
                     pk2(b2r[2 * 128 + o], b2r[3 * 128 + o]),
                     pk2(b2r[4 * 128 + o], b2r[5 * 128 + o]),
                     pk2(b2r[6 * 128 + o], b2r[7 * 128 + o])};
      }
      f32x16 z{};
      #pragma unroll
      for (int tt = 0; tt < 2; ++tt) acc2[ot][tt] = MFMA32(af, gf[tt], z);
    }
  }

  // ---- chunk loop: 64 chunks = 8 experts x 8 h-tiles; ring-3, prefetch dist 2
  const u32 rb1 = (u32)(col * 256);
  const u32 x1 = (u32)((l & 15) << 4);
  // prefetch source pointers start at chunk 2, advance 8192/chunk
  const char* sp1 = img1 + 16384 + w * 2048 + l * 16;
  const char* sp2 = img2 + 16384 + w * 2048 + l * 16;
  int cur = 0, wr = 2;

  #pragma unroll 1
  for (int e = 0; e < 8; ++e) {
    const float* gTe = (const float*)(smem + LDS_G) + e * 256 + w * 64 + col;
    const float g0 = gTe[0];
    const float g1 = gTe[32];
    const float* b1e = (const float*)(smem + LDS_B1) + e * 256 + hi * 4;

    #pragma unroll 1
    for (int ht = 0; ht < 8; ++ht) {
      const int n = e * 8 + ht;
      if (n > 0) {
        if (n < 63) asm volatile("s_waitcnt vmcnt(4)" ::: "memory");
        else        asm volatile("s_waitcnt vmcnt(0)" ::: "memory");
        __builtin_amdgcn_s_barrier();
        asm volatile("" ::: "memory");  // no LDS reads hoisted above barrier
        __builtin_amdgcn_sched_barrier(0);
      }

      // issue prefetch of chunk n+2 into ring[wr] (overlaps this chunk's compute)
      if (n + 2 < 64) {
        char* d1 = smem + wr * 16384 + w * 2048;
        char* d2 = d1 + 8192;
        load_lds16(sp1,        d1);
        load_lds16(sp1 + 1024, d1 + 1024);
        load_lds16(sp2,        d2);
        load_lds16(sp2 + 1024, d2 + 1024);
      }
      sp1 += 8192; sp2 += 8192;

      // --- GEMM1: D1[32h x 64t] for h in [32*ht, 32*ht+32)
      const char* w1c = smem + cur * 16384;
      f32x16 a1_0{}, a1_1{};
      __builtin_amdgcn_s_setprio(1);
      #pragma unroll
      for (int ks = 0; ks < 8; ++ks) {
        u32 off = rb1 + (((u32)((ks * 2 + hi) * 16)) ^ x1);
        u32x4 frag = *(const u32x4*)(w1c + off);
        a1_0 = MFMA32(frag, xf[0][ks], a1_0);
        a1_1 = MFMA32(frag, xf[1][ks], a1_1);
      }
      __builtin_amdgcn_s_setprio(0);

      // --- epilogue: +b1, relu, *gate, pack bf16, permlane -> GEMM2 B-frags
      u32x4 hf[2][2];
      const float* b1b = b1e + ht * 32;
      #pragma unroll
      for (int tt = 0; tt < 2; ++tt) {
        const f32x16& a1 = tt ? a1_1 : a1_0;
        const float g = tt ? g1 : g0;
        u32 u[8];
        #pragma unroll
        for (int rg = 0; rg < 4; ++rg) {
          f32x4 bb = *(const f32x4*)(b1b + rg * 8);
          float h0 = fmaxf(a1[rg * 4 + 0] + bb.x, 0.f) * g;
          float h1 = fmaxf(a1[rg * 4 + 1] + bb.y, 0.f) * g;
          float h2 = fmaxf(a1[rg * 4 + 2] + bb.z, 0.f) * g;
          float h3 = fmaxf(a1[rg * 4 + 3] + bb.w, 0.f) * g;
          u[rg * 2 + 0] = pk2(h0, h1);
          u[rg * 2 + 1] = pk2(h2, h3);
        }
        pl32swap(u[0], u[2]);
        pl32swap(u[1], u[3]);
        pl32swap(u[4], u[6]);
        pl32swap(u[5], u[7]);
        hf[0][tt] = (u32x4){u[0], u[1], u[2], u[3]};
        hf[1][tt] = (u32x4){u[4], u[5], u[6], u[7]};
      }

      // --- GEMM2: acc2[o][t] += w2q[o][k-slice] * hid[k-slice][t]
      const char* w2c = w1c + 8192;
      __builtin_amdgcn_s_setprio(1);
      #pragma unroll
      for (int ks2 = 0; ks2 < 2; ++ks2) {
        #pragma unroll
        for (int ot = 0; ot < 4; ++ot) {
          u32 og = (u32)(ot * 8 + (col >> 2));
          u32 slot = (u32)((col & 3) * 4 + ks2 * 2 + hi);
          u32 off = og * 256 + ((slot * 16) ^ ((og & 7) << 4));
          u32x4 af = *(const u32x4*)(w2c + off);
          acc2[ot][0] = MFMA32(af, hf[ks2][0], acc2[ot][0]);
          acc2[ot][1] = MFMA32(af, hf[ks2][1], acc2[ot][1]);
        }
      }
      __builtin_amdgcn_s_setprio(0);

      cur = (cur == 2) ? 0 : cur + 1;
      wr  = (wr  == 2) ? 0 : wr  + 1;
    }
  }

  // ---- store D2[o][t] -> out[t][o]
  #pragma unroll
  for (int ot = 0; ot < 4; ++ot) {
    #pragma unroll
    for (int tt = 0; tt < 2; ++tt) {
      const f32x16& a = acc2[ot][tt];
      float* op = out + (size_t)(tokw + tt * 32 + col) * 128 + ot * 32 + hi * 4;
      #pragma unroll
      for (int rg = 0; rg < 4; ++rg)
        *(f32x4*)(op + rg * 8) =
            (f32x4){a[rg * 4 + 0], a[rg * 4 + 1], a[rg * 4 + 2], a[rg * 4 + 3]};
    }
  }
}

extern "C" void kernel_launch(void* const* d_in, const int* in_sizes, int n_in,
                              void* d_out, int out_size, void* d_ws, size_t ws_size,
                              hipStream_t stream) {
  const float* x  = (const float*)d_in[0];
  const float* w1 = (const float*)d_in[1];
  const float* b1 = (const float*)d_in[2];
  const float* w2 = (const float*)d_in[3];
  const float* b2 = (const float*)d_in[4];
  const float* wg = (const float*)d_in[5];
  const float* bg = (const float*)d_in[6];
  float* out = (float*)d_out;

  if (ws_size < 1048640) return;
  char* ws = (char*)d_ws;
  char* img1 = ws;                        // 8 * 64KB
  char* img2 = ws + 524288;               // 8 * 64KB
  float* alphas = (float*)(ws + 1048576); // 16 f32

  int ntok = in_sizes[0] / 128;
  int nblk = ntok / 256;

  qalpha<<<16, 256, 0, stream>>>(w1, w2, alphas);
  qimg<<<256, 256, 0, stream>>>(w1, w2, alphas, img1, img2);

  hipFuncSetAttribute(reinterpret_cast<const void*>(moe_main),
                      hipFuncAttributeMaxDynamicSharedMemorySize, SMEM_BYTES);
  moe_main<<<nblk, 256, SMEM_BYTES, stream>>>(x, b1, b2, wg, bg, img1, img2, out);
}